// Round 1
// baseline (382.593 us; speedup 1.0000x reference)
//
#include <hip/hip_runtime.h>

#define T 2048
#define SD 1024
#define ED 1024
#define HID 150
#define MAXW 10

typedef float f32x4 __attribute__((ext_vector_type(4)));

// ---------------------------------------------------------------------------
// Kernel 1: per-token MLP score -> stores exp(score).
// THIS ROUND: 512 threads (8 waves) per 4-token block. Grid stays 512 blocks
// (2 blocks/CU) but waves/CU doubles 8 -> 16 (4/SIMD), halving the
// latency-bound layer-1/layer-2 iteration counts per wave. w1 row-pairs remain
// register double-buffered (prefetch next pair before current compute).
// ---------------------------------------------------------------------------
__global__ __launch_bounds__(512) void mlp_scores_kernel(
    const float* __restrict__ states,
    const float* __restrict__ w1, const float* __restrict__ b1,
    const float* __restrict__ w2, const float* __restrict__ b2,
    const float* __restrict__ w3, const float* __restrict__ b3,
    float* __restrict__ expA)
{
    const int t0 = blockIdx.x * 4;
    __shared__ float4 s_state[4][256];
    __shared__ float s_h1[4][192];   // padded to 192, zero-filled tail
    __shared__ float s_h2[4][192];
    const int tid = threadIdx.x;

    for (int i = tid; i < 4 * 192; i += 512) {
        (&s_h1[0][0])[i] = 0.f;
        (&s_h2[0][0])[i] = 0.f;
    }
    {
        const float4* src = (const float4*)(states + (size_t)t0 * SD);
        float4* dst = &s_state[0][0];
        for (int i = tid; i < 4 * SD / 4; i += 512) dst[i] = src[i];
    }
    __syncthreads();

    const int lane = tid & 63;
    const int wave = tid >> 6;

    // ---- layer 1: h1 = relu(states @ w1^T + b1); wave w owns pairs {2w,2w+1}+16k ----
    {
        int j = wave * 2;
        float4 wra[4], wrb[4];
        {
            const float4* w4a = (const float4*)(w1 + (size_t)j * SD);
#pragma unroll
            for (int m = 0; m < 4; ++m) {
                wra[m] = w4a[m * 64 + lane];
                wrb[m] = w4a[256 + m * 64 + lane];
            }
        }
        while (j < HID) {
            const int jn = j + 16;
            const int jp = (jn < HID) ? jn : j;   // clamp: last iter reloads self
            float4 nra[4], nrb[4];
            {
                const float4* n4a = (const float4*)(w1 + (size_t)jp * SD);
#pragma unroll
                for (int m = 0; m < 4; ++m) {      // prefetch BEFORE compute
                    nra[m] = n4a[m * 64 + lane];
                    nrb[m] = n4a[256 + m * 64 + lane];
                }
            }
            const float bja = b1[j];
            const float bjb = b1[j + 1];
#pragma unroll
            for (int t = 0; t < 4; ++t) {
                float acc0 = 0.f, acc1 = 0.f;
#pragma unroll
                for (int m = 0; m < 4; ++m) {
                    const float4 sv = s_state[t][m * 64 + lane];  // ds_read_b128
                    acc0 += sv.x * wra[m].x + sv.y * wra[m].y
                          + sv.z * wra[m].z + sv.w * wra[m].w;
                    acc1 += sv.x * wrb[m].x + sv.y * wrb[m].y
                          + sv.z * wrb[m].z + sv.w * wrb[m].w;
                }
#pragma unroll
                for (int off = 32; off > 0; off >>= 1) {
                    acc0 += __shfl_down(acc0, off, 64);
                    acc1 += __shfl_down(acc1, off, 64);
                }
                if (lane == 0) {
                    s_h1[t][j]     = fmaxf(acc0 + bja, 0.f);
                    s_h1[t][j + 1] = fmaxf(acc1 + bjb, 0.f);
                }
            }
#pragma unroll
            for (int m = 0; m < 4; ++m) { wra[m] = nra[m]; wrb[m] = nrb[m]; }
            j = jn;
        }
    }
    __syncthreads();

    // ---- layer 2: h2 = relu(h1 @ w2^T + b2); 8 waves stride 8 ----
    for (int j = wave; j < HID; j += 8) {
        const float* wrow = w2 + (size_t)j * HID;
        const float wa = wrow[lane];
        const float wb = wrow[lane + 64];
        const float wc = (lane + 128 < HID) ? wrow[lane + 128] : 0.f;
        const float bj = b2[j];
#pragma unroll
        for (int t = 0; t < 4; ++t) {
            float acc = s_h1[t][lane] * wa + s_h1[t][lane + 64] * wb
                      + s_h1[t][lane + 128] * wc;
#pragma unroll
            for (int off = 32; off > 0; off >>= 1) acc += __shfl_down(acc, off, 64);
            if (lane == 0) s_h2[t][j] = fmaxf(acc + bj, 0.f);
        }
    }
    __syncthreads();

    // ---- layer 3: scalar score; waves 0..3 handle tokens 0..3 ----
    if (wave < 4) {
        const int t = wave;
        const float wa = w3[lane];
        const float wb = w3[lane + 64];
        const float wc = (lane + 128 < HID) ? w3[lane + 128] : 0.f;
        float acc = s_h2[t][lane] * wa + s_h2[t][lane + 64] * wb
                  + s_h2[t][lane + 128] * wc;
#pragma unroll
        for (int off = 32; off > 0; off >>= 1) acc += __shfl_down(acc, off, 64);
        if (lane == 0) expA[t0 + t] = expf(acc + b3[0]);
    }
}

// ---------------------------------------------------------------------------
// Kernel 2 — RESTRUCTURED: width-major, 4 consecutive starts per block.
// Old layout (block = one start, 10 width-scattered rows) produced ~40
// concurrent 12 KB write streams per CU -> near-random dirty-line eviction
// from L2 -> ~1.7 TB/s effective HBM write BW. New layout: block (n, s0)
// writes rows s0..s0+3 of width-segment n = 48 KB CONTIGUOUS, and
// consecutive blocks continue the run (fill-like stream, 6.4 TB/s evidence).
// Prefix P,S built once (n FMAs), then slid with +-E*e updates; the
// subtracted embed rows are L1-resident (loaded by this block moments ago).
// XCD-chunked bijective swizzle (5112 % 8 == 0) gives each XCD one
// contiguous ~31 MB output range and a localized embed working set.
// ---------------------------------------------------------------------------
__global__ __launch_bounds__(256) void span_kernel(
    const float* __restrict__ embeds,
    const float* __restrict__ states,
    const float* __restrict__ expA,
    float* __restrict__ out)
{
    const int NB = 5112;                       // sum over n of ceil((T-n+1)/4)
    int b = blockIdx.x;
    b = (b & 7) * (NB / 8) + (b >> 3);         // XCD-chunked swizzle (bijective)

    // blocks-per-segment prefix: nb = {512,512,512,512,511,511,511,511,510,510}
    const int bstart[11] = {0, 512, 1024, 1536, 2048, 2559, 3070, 3581, 4092, 4602, 5112};
    // output row offset of each width segment: off_n = sum_{m<n} (T-m+1)
    const int rowoff[10] = {0, 2048, 4095, 6141, 8186, 10230, 12273, 14315, 16356, 18396};

    int n = 1;
#pragma unroll
    for (int m = 2; m <= MAXW; ++m) if (b >= bstart[m - 1]) n = m;
    const int s0 = (b - bstart[n - 1]) * 4;

    const int c = threadIdx.x;                 // f32x4 column within 1024-float seg
    const f32x4* emb4 = (const f32x4*)embeds;
    const f32x4* st4  = (const f32x4*)states;

    // build prefix for window [s0, s0+n-1] (always valid: each block has >=1 row)
    f32x4 P = (f32x4)(0.f);
    float S = 0.f;
    for (int i = 0; i < n; ++i) {
        const float E = expA[s0 + i];
        P += E * emb4[(size_t)(s0 + i) * 256 + c];
        S += E;
    }

    const int rowbase = rowoff[n - 1];
#pragma unroll
    for (int g = 0; g < 4; ++g) {
        const int s = s0 + g;
        if (s > T - n) break;                  // tail guard (scalar, uniform)
        const f32x4 stv = st4[(size_t)s * 256 + c];
        const f32x4 sev = st4[(size_t)(s + n - 1) * 256 + c];
        const float inv = __builtin_amdgcn_rcpf(S);   // ~1 ulp, chain is 1 instr
        f32x4* orow = (f32x4*)(out + (size_t)(rowbase + s) * 3072);
        orow[c]       = stv;
        orow[256 + c] = sev;
        orow[512 + c] = P * inv;
        if (g < 3 && s + 1 <= T - n) {         // slide window: +row(s+n) -row(s)
            const float Eo = expA[s];
            const float Ei = expA[s + n];
            P += Ei * emb4[(size_t)(s + n) * 256 + c]
               - Eo * emb4[(size_t)s * 256 + c];      // row s: L1 hit
            S += Ei - Eo;
        }
    }
}

extern "C" void kernel_launch(void* const* d_in, const int* in_sizes, int n_in,
                              void* d_out, int out_size, void* d_ws, size_t ws_size,
                              hipStream_t stream) {
    const float* embeds = (const float*)d_in[0];
    const float* states = (const float*)d_in[1];
    const float* w1 = (const float*)d_in[2];
    const float* b1 = (const float*)d_in[3];
    const float* w2 = (const float*)d_in[4];
    const float* b2 = (const float*)d_in[5];
    const float* w3 = (const float*)d_in[6];
    const float* b3 = (const float*)d_in[7];
    float* out = (float*)d_out;
    float* expA = (float*)d_ws;  // T floats of scratch

    mlp_scores_kernel<<<T / 4, 512, 0, stream>>>(states, w1, b1, w2, b2, w3, b3, expA);
    span_kernel<<<5112, 256, 0, stream>>>(embeds, states, expA, out);
}

// Round 2
// 369.306 us; speedup vs baseline: 1.0360x; 1.0360x over previous
//
#include <hip/hip_runtime.h>

#define T 2048
#define SD 1024
#define ED 1024
#define HID 150
#define MAXW 10

typedef float f32x4 __attribute__((ext_vector_type(4)));

// ---------------------------------------------------------------------------
// Kernel 1: per-token MLP score -> stores exp(score) (softmax numerator).
// EXACT R0 version (known-good at 358 us total): 4 tokens/block, 256 threads,
// w1 row-pairs register double-buffered. Reverted from the 512-thread R1
// variant to isolate the span-kernel change this round.
// ---------------------------------------------------------------------------
__global__ __launch_bounds__(256) void mlp_scores_kernel(
    const float* __restrict__ states,
    const float* __restrict__ w1, const float* __restrict__ b1,
    const float* __restrict__ w2, const float* __restrict__ b2,
    const float* __restrict__ w3, const float* __restrict__ b3,
    float* __restrict__ expA)
{
    const int t0 = blockIdx.x * 4;
    __shared__ float4 s_state[4][256];
    __shared__ float s_h1[4][192];   // padded to 192, zero-filled tail
    __shared__ float s_h2[4][192];
    const int tid = threadIdx.x;

    for (int i = tid; i < 4 * 192; i += 256) {
        (&s_h1[0][0])[i] = 0.f;
        (&s_h2[0][0])[i] = 0.f;
    }
    {
        const float4* src = (const float4*)(states + (size_t)t0 * SD);
        float4* dst = &s_state[0][0];
        for (int i = tid; i < 4 * SD / 4; i += 256) dst[i] = src[i];
    }
    __syncthreads();

    const int lane = tid & 63;
    const int wave = tid >> 6;

    // ---- layer 1: h1 = relu(states @ w1^T + b1), j-pairs, double-buffered ----
    {
        int j = wave * 2;
        float4 wra[4], wrb[4];
        {
            const float4* w4a = (const float4*)(w1 + (size_t)j * SD);
#pragma unroll
            for (int m = 0; m < 4; ++m) {
                wra[m] = w4a[m * 64 + lane];
                wrb[m] = w4a[256 + m * 64 + lane];
            }
        }
        while (j < HID) {
            const int jn = j + 8;
            const int jp = (jn < HID) ? jn : j;   // clamp: last iter reloads self
            float4 nra[4], nrb[4];
            {
                const float4* n4a = (const float4*)(w1 + (size_t)jp * SD);
#pragma unroll
                for (int m = 0; m < 4; ++m) {      // prefetch BEFORE compute
                    nra[m] = n4a[m * 64 + lane];
                    nrb[m] = n4a[256 + m * 64 + lane];
                }
            }
            const float bja = b1[j];
            const float bjb = b1[j + 1];
#pragma unroll
            for (int t = 0; t < 4; ++t) {
                float acc0 = 0.f, acc1 = 0.f;
#pragma unroll
                for (int m = 0; m < 4; ++m) {
                    const float4 sv = s_state[t][m * 64 + lane];  // ds_read_b128
                    acc0 += sv.x * wra[m].x + sv.y * wra[m].y
                          + sv.z * wra[m].z + sv.w * wra[m].w;
                    acc1 += sv.x * wrb[m].x + sv.y * wrb[m].y
                          + sv.z * wrb[m].z + sv.w * wrb[m].w;
                }
#pragma unroll
                for (int off = 32; off > 0; off >>= 1) {
                    acc0 += __shfl_down(acc0, off, 64);
                    acc1 += __shfl_down(acc1, off, 64);
                }
                if (lane == 0) {
                    s_h1[t][j]     = fmaxf(acc0 + bja, 0.f);
                    s_h1[t][j + 1] = fmaxf(acc1 + bjb, 0.f);
                }
            }
#pragma unroll
            for (int m = 0; m < 4; ++m) { wra[m] = nra[m]; wrb[m] = nrb[m]; }
            j = jn;
        }
    }
    __syncthreads();

    // ---- layer 2: h2 = relu(h1 @ w2^T + b2) ----
    for (int j = wave; j < HID; j += 4) {
        const float* wrow = w2 + (size_t)j * HID;
        const float wa = wrow[lane];
        const float wb = wrow[lane + 64];
        const float wc = (lane + 128 < HID) ? wrow[lane + 128] : 0.f;
        const float bj = b2[j];
#pragma unroll
        for (int t = 0; t < 4; ++t) {
            float acc = s_h1[t][lane] * wa + s_h1[t][lane + 64] * wb
                      + s_h1[t][lane + 128] * wc;
#pragma unroll
            for (int off = 32; off > 0; off >>= 1) acc += __shfl_down(acc, off, 64);
            if (lane == 0) s_h2[t][j] = fmaxf(acc + bj, 0.f);
        }
    }
    __syncthreads();

    // ---- layer 3: scalar score; wave t handles token t ----
    {
        const int t = wave;
        const float wa = w3[lane];
        const float wb = w3[lane + 64];
        const float wc = (lane + 128 < HID) ? w3[lane + 128] : 0.f;
        float acc = s_h2[t][lane] * wa + s_h2[t][lane + 64] * wb
                  + s_h2[t][lane + 128] * wc;
#pragma unroll
        for (int off = 32; off > 0; off >>= 1) acc += __shfl_down(acc, off, 64);
        if (lane == 0) expA[t0 + t] = expf(acc + b3[0]);
    }
}

// ---------------------------------------------------------------------------
// Kernel 2 — width-major, 8 consecutive starts per block, NATURAL block order
// (no XCD swizzle this round: the swizzle assumed blockIdx%8==XCD; if that
// mapping is wrong it scatters the write front. The fill — the only 6.5 TB/s
// store evidence on this box — uses natural order with ONE moving contiguous
// write front; this kernel now reproduces that pattern: block b writes a
// 96 KB contiguous output chunk and consecutive b continue the run).
// Prefix P,S built once (n FMAs), then slid with +-E*e updates; subtracted
// embed rows are L1-resident (read by this block moments earlier).
// ---------------------------------------------------------------------------
__global__ __launch_bounds__(256) void span_kernel(
    const float* __restrict__ embeds,
    const float* __restrict__ states,
    const float* __restrict__ expA,
    float* __restrict__ out)
{
    const int b = blockIdx.x;  // natural order, 2558 blocks

    // blocks-per-segment prefix (8 rows/block):
    // nb = {256,256,256,256,256,256,256,256,255,255}
    const int bstart[11] = {0, 256, 512, 768, 1024, 1280, 1536, 1792, 2048, 2303, 2558};
    // output row offset of each width segment: off_n = sum_{m<n} (T-m+1)
    const int rowoff[10] = {0, 2048, 4095, 6141, 8186, 10230, 12273, 14315, 16356, 18396};

    int n = 1;
#pragma unroll
    for (int m = 2; m <= MAXW; ++m) if (b >= bstart[m - 1]) n = m;
    const int s0 = (b - bstart[n - 1]) * 8;

    const int c = threadIdx.x;                 // f32x4 column within 1024-float seg
    const f32x4* emb4 = (const f32x4*)embeds;
    const f32x4* st4  = (const f32x4*)states;

    // build prefix for window [s0, s0+n-1] (always valid: each block has >=1 row)
    f32x4 P = (f32x4)(0.f);
    float S = 0.f;
    for (int i = 0; i < n; ++i) {
        const float E = expA[s0 + i];
        P += E * emb4[(size_t)(s0 + i) * 256 + c];
        S += E;
    }

    const int rowbase = rowoff[n - 1];
#pragma unroll
    for (int g = 0; g < 8; ++g) {
        const int s = s0 + g;
        if (s > T - n) break;                  // tail guard (uniform)
        const f32x4 stv = st4[(size_t)s * 256 + c];
        const f32x4 sev = st4[(size_t)(s + n - 1) * 256 + c];
        const float inv = __builtin_amdgcn_rcpf(S);
        f32x4* orow = (f32x4*)(out + (size_t)(rowbase + s) * 3072);
        orow[c]       = stv;
        orow[256 + c] = sev;
        orow[512 + c] = P * inv;
        if (g < 7 && s + 1 <= T - n) {         // slide window: +row(s+n) -row(s)
            const float Eo = expA[s];
            const float Ei = expA[s + n];
            P += Ei * emb4[(size_t)(s + n) * 256 + c]
               - Eo * emb4[(size_t)s * 256 + c];      // row s: L1 hit
            S += Ei - Eo;
        }
    }
}

extern "C" void kernel_launch(void* const* d_in, const int* in_sizes, int n_in,
                              void* d_out, int out_size, void* d_ws, size_t ws_size,
                              hipStream_t stream) {
    const float* embeds = (const float*)d_in[0];
    const float* states = (const float*)d_in[1];
    const float* w1 = (const float*)d_in[2];
    const float* b1 = (const float*)d_in[3];
    const float* w2 = (const float*)d_in[4];
    const float* b2 = (const float*)d_in[5];
    const float* w3 = (const float*)d_in[6];
    const float* b3 = (const float*)d_in[7];
    float* out = (float*)d_out;
    float* expA = (float*)d_ws;  // T floats of scratch

    mlp_scores_kernel<<<T / 4, 256, 0, stream>>>(states, w1, b1, w2, b2, w3, b3, expA);
    span_kernel<<<2558, 256, 0, stream>>>(embeds, states, expA, out);
}

// Round 4
// 361.162 us; speedup vs baseline: 1.0593x; 1.0226x over previous
//
#include <hip/hip_runtime.h>

#define T 2048
#define SD 1024
#define ED 1024
#define HID 150
#define MAXW 10

typedef float f32x4 __attribute__((ext_vector_type(4)));

// ---------------------------------------------------------------------------
// Kernel 1: per-token MLP score -> stores exp(score) (softmax numerator).
// EXACT R0 version (known-good): 4 tokens/block, 256 threads, w1 row-pairs
// register double-buffered.
// ---------------------------------------------------------------------------
__global__ __launch_bounds__(256) void mlp_scores_kernel(
    const float* __restrict__ states,
    const float* __restrict__ w1, const float* __restrict__ b1,
    const float* __restrict__ w2, const float* __restrict__ b2,
    const float* __restrict__ w3, const float* __restrict__ b3,
    float* __restrict__ expA)
{
    const int t0 = blockIdx.x * 4;
    __shared__ float4 s_state[4][256];
    __shared__ float s_h1[4][192];   // padded to 192, zero-filled tail
    __shared__ float s_h2[4][192];
    const int tid = threadIdx.x;

    for (int i = tid; i < 4 * 192; i += 256) {
        (&s_h1[0][0])[i] = 0.f;
        (&s_h2[0][0])[i] = 0.f;
    }
    {
        const float4* src = (const float4*)(states + (size_t)t0 * SD);
        float4* dst = &s_state[0][0];
        for (int i = tid; i < 4 * SD / 4; i += 256) dst[i] = src[i];
    }
    __syncthreads();

    const int lane = tid & 63;
    const int wave = tid >> 6;

    // ---- layer 1: h1 = relu(states @ w1^T + b1), j-pairs, double-buffered ----
    {
        int j = wave * 2;
        float4 wra[4], wrb[4];
        {
            const float4* w4a = (const float4*)(w1 + (size_t)j * SD);
#pragma unroll
            for (int m = 0; m < 4; ++m) {
                wra[m] = w4a[m * 64 + lane];
                wrb[m] = w4a[256 + m * 64 + lane];
            }
        }
        while (j < HID) {
            const int jn = j + 8;
            const int jp = (jn < HID) ? jn : j;   // clamp: last iter reloads self
            float4 nra[4], nrb[4];
            {
                const float4* n4a = (const float4*)(w1 + (size_t)jp * SD);
#pragma unroll
                for (int m = 0; m < 4; ++m) {      // prefetch BEFORE compute
                    nra[m] = n4a[m * 64 + lane];
                    nrb[m] = n4a[256 + m * 64 + lane];
                }
            }
            const float bja = b1[j];
            const float bjb = b1[j + 1];
#pragma unroll
            for (int t = 0; t < 4; ++t) {
                float acc0 = 0.f, acc1 = 0.f;
#pragma unroll
                for (int m = 0; m < 4; ++m) {
                    const float4 sv = s_state[t][m * 64 + lane];  // ds_read_b128
                    acc0 += sv.x * wra[m].x + sv.y * wra[m].y
                          + sv.z * wra[m].z + sv.w * wra[m].w;
                    acc1 += sv.x * wrb[m].x + sv.y * wrb[m].y
                          + sv.z * wrb[m].z + sv.w * wrb[m].w;
                }
#pragma unroll
                for (int off = 32; off > 0; off >>= 1) {
                    acc0 += __shfl_down(acc0, off, 64);
                    acc1 += __shfl_down(acc1, off, 64);
                }
                if (lane == 0) {
                    s_h1[t][j]     = fmaxf(acc0 + bja, 0.f);
                    s_h1[t][j + 1] = fmaxf(acc1 + bjb, 0.f);
                }
            }
#pragma unroll
            for (int m = 0; m < 4; ++m) { wra[m] = nra[m]; wrb[m] = nrb[m]; }
            j = jn;
        }
    }
    __syncthreads();

    // ---- layer 2: h2 = relu(h1 @ w2^T + b2) ----
    for (int j = wave; j < HID; j += 4) {
        const float* wrow = w2 + (size_t)j * HID;
        const float wa = wrow[lane];
        const float wb = wrow[lane + 64];
        const float wc = (lane + 128 < HID) ? wrow[lane + 128] : 0.f;
        const float bj = b2[j];
#pragma unroll
        for (int t = 0; t < 4; ++t) {
            float acc = s_h1[t][lane] * wa + s_h1[t][lane + 64] * wb
                      + s_h1[t][lane + 128] * wc;
#pragma unroll
            for (int off = 32; off > 0; off >>= 1) acc += __shfl_down(acc, off, 64);
            if (lane == 0) s_h2[t][j] = fmaxf(acc + bj, 0.f);
        }
    }
    __syncthreads();

    // ---- layer 3: scalar score; wave t handles token t ----
    {
        const int t = wave;
        const float wa = w3[lane];
        const float wb = w3[lane + 64];
        const float wc = (lane + 128 < HID) ? w3[lane + 128] : 0.f;
        float acc = s_h2[t][lane] * wa + s_h2[t][lane + 64] * wb
                  + s_h2[t][lane + 128] * wc;
#pragma unroll
        for (int off = 32; off > 0; off >>= 1) acc += __shfl_down(acc, off, 64);
        if (lane == 0) expA[t0 + t] = expf(acc + b3[0]);
    }
}

// ---------------------------------------------------------------------------
// Kernel 2: EXACT R0 structure (start-major, all 21 loads issued upfront —
// empirically the fastest of the three span variants tried) with ONE change:
// the output stores are NONTEMPORAL. Rationale: the 251.6 MB output is
// write-once/never-read; normal stores allocate dirty lines that churn the
// 4 MB/XCD L2 (and L3), continuously evicting the 16 MB embed/state working
// set that has ~10x block reuse. `nt` stores keep the read working set
// cache-resident while streaming the output at HBM rate.
// ---------------------------------------------------------------------------
__global__ __launch_bounds__(256) void span_kernel(
    const float* __restrict__ embeds,
    const float* __restrict__ states,
    const float* __restrict__ expA,
    float* __restrict__ out)
{
    const int s = blockIdx.x;
    const int c = threadIdx.x;  // float4 index within a 1024-float segment

    const f32x4 st_s = ((const f32x4*)(states + (size_t)s * SD))[c];

    f32x4 P = (f32x4)(0.f);
    float S = 0.f;

    if (s <= T - MAXW) {
        int base = 0;
#pragma unroll
        for (int i = 0; i < MAXW; ++i) {
            const float E = expA[s + i];
            const f32x4 e  = ((const f32x4*)(embeds + (size_t)(s + i) * ED))[c];
            const f32x4 se = ((const f32x4*)(states + (size_t)(s + i) * SD))[c];
            P += E * e;
            S += E;
            const float inv = 1.f / S;
            f32x4* orow = (f32x4*)(out + (size_t)(base + s) * 3072);
            __builtin_nontemporal_store(st_s, &orow[c]);
            __builtin_nontemporal_store(se, &orow[256 + c]);
            __builtin_nontemporal_store(P * inv, &orow[512 + c]);
            base += T - i;
        }
    } else {
        int base = 0;
        for (int i = 0; i < MAXW; ++i) {
            if (s + i < T) {
                const float E = expA[s + i];
                const f32x4 e  = ((const f32x4*)(embeds + (size_t)(s + i) * ED))[c];
                const f32x4 se = ((const f32x4*)(states + (size_t)(s + i) * SD))[c];
                P += E * e;
                S += E;
                const float inv = 1.f / S;
                f32x4* orow = (f32x4*)(out + (size_t)(base + s) * 3072);
                __builtin_nontemporal_store(st_s, &orow[c]);
                __builtin_nontemporal_store(se, &orow[256 + c]);
                __builtin_nontemporal_store(P * inv, &orow[512 + c]);
            }
            base += T - i;
        }
    }
}

extern "C" void kernel_launch(void* const* d_in, const int* in_sizes, int n_in,
                              void* d_out, int out_size, void* d_ws, size_t ws_size,
                              hipStream_t stream) {
    const float* embeds = (const float*)d_in[0];
    const float* states = (const float*)d_in[1];
    const float* w1 = (const float*)d_in[2];
    const float* b1 = (const float*)d_in[3];
    const float* w2 = (const float*)d_in[4];
    const float* b2 = (const float*)d_in[5];
    const float* w3 = (const float*)d_in[6];
    const float* b3 = (const float*)d_in[7];
    float* out = (float*)d_out;
    float* expA = (float*)d_ws;  // T floats of scratch

    mlp_scores_kernel<<<T / 4, 256, 0, stream>>>(states, w1, b1, w2, b2, w3, b3, expA);
    span_kernel<<<T, 256, 0, stream>>>(embeds, states, expA, out);
}